// Round 1
// baseline (263.408 us; speedup 1.0000x reference)
//
#include <hip/hip_runtime.h>
#include <math.h>

// B=8, C=64, H=512, W=512, K=8, HID=64, nh=nw=64, L=4096
// Fused single-pass kernel:
//   block = 256 threads = (c in [0,64)) x (pw in [0,4)), one block per
//   (b, patch-row ph, group of 4 patch-cols). Each thread holds one 8x8
//   patch (one channel) in 16 float4 registers; x is read exactly once
//   and out written exactly once -> traffic floor ~1.07 GiB.

static __device__ __forceinline__ float gelu_erf(float x) {
    // exact-erf GELU, matching torch/jax approximate=False
    return 0.5f * x * (1.0f + erff(x * 0.70710678118654752f));
}

__global__ __launch_bounds__(256) void afpm_fused(
    const float* __restrict__ x,
    const float* __restrict__ w1k, const float* __restrict__ b1k,
    const float* __restrict__ w2k, const float* __restrict__ b2k,
    const float* __restrict__ w1b, const float* __restrict__ b1b,
    const float* __restrict__ w2b, const float* __restrict__ b2b,
    const float* __restrict__ conv_w, const float* __restrict__ conv_b,
    float* __restrict__ out)
{
    constexpr int C   = 64;
    constexpr int H   = 512;
    constexpr int W   = 512;
    constexpr int HID = 64;
    constexpr int PWG = 4;   // patches per block

    const int tid = threadIdx.x;
    const int pw  = tid & (PWG - 1);   // 0..3  patch within group
    const int c   = tid >> 2;          // 0..63 channel
    const int pwg = blockIdx.x;        // 0..15 patch-col group
    const int ph  = blockIdx.y;        // 0..63 patch row
    const int b   = blockIdx.z;        // 0..7  batch

    const int pw_glob = pwg * PWG + pw;        // 0..63 global patch col

    __shared__ float gk[PWG][HID];   // gelu hidden, kernel-MLP
    __shared__ float gb[PWG][HID];   // gelu hidden, bias-MLP
    __shared__ float pk[PWG][HID];   // dynamic 8x8 kernel per patch
    __shared__ float f0[C][PWG];     // feats before conv (incl. pb)
    __shared__ float ft[C][PWG];     // feats after conv
    __shared__ float pbs[PWG];       // dynamic bias per patch

    // ---- issue all pixel loads first (latency hidden under MLP compute) ----
    const size_t base = (((size_t)b * C + c) * H + (size_t)ph * 8) * W
                        + (size_t)pw_glob * 8;
    const float* xp = x + base;
    float4 v[16];
#pragma unroll
    for (int r = 0; r < 8; ++r) {
        v[2 * r + 0] = *(const float4*)(xp + (size_t)r * W);
        v[2 * r + 1] = *(const float4*)(xp + (size_t)r * W + 4);
    }

    // ---- per-patch normalized center distance ----
    const float py = (float)(ph * 8) + 4.0f - 256.0f;
    const float px = (float)(pw_glob * 8) + 4.0f - 256.0f;
    const float dd = sqrtf(py * py + px * px) * (1.0f / 362.03867196751236f);

    // ---- MLP hidden layer: thread (c,pw) computes hidden unit h=c, patch pw
    {
        const int h = c;
        gk[pw][h] = gelu_erf(dd * w1k[h] + b1k[h]);
        gb[pw][h] = gelu_erf(dd * w1b[h] + b1b[h]);
    }
    __syncthreads();

    // ---- MLP output layer: pk[pw][j] for j=c; pb by the c==0 threads ----
    {
        const int j = c;
        float s = b2k[j];
#pragma unroll 8
        for (int h = 0; h < HID; ++h)
            s += gk[pw][h] * w2k[h * HID + j];
        pk[pw][j] = s;

        if (c == 0) {
            float t = b2b[0];
            for (int h = 0; h < HID; ++h)
                t += gb[pw][h] * w2b[h];
            pbs[pw] = t;
        }
    }
    __syncthreads();

    // ---- feats0: dot(patch pixels, pk) + pb ----
    {
        float s = 0.0f;
#pragma unroll
        for (int r = 0; r < 8; ++r) {
            const float4 a = v[2 * r + 0];
            const float4 q = v[2 * r + 1];
            s += a.x * pk[pw][r * 8 + 0] + a.y * pk[pw][r * 8 + 1]
               + a.z * pk[pw][r * 8 + 2] + a.w * pk[pw][r * 8 + 3];
            s += q.x * pk[pw][r * 8 + 4] + q.y * pk[pw][r * 8 + 5]
               + q.z * pk[pw][r * 8 + 6] + q.w * pk[pw][r * 8 + 7];
        }
        f0[c][pw] = s + pbs[pw];
    }
    __syncthreads();

    // ---- 1x1 conv across channels: thread (o=c, pw) ----
    {
        const int o = c;
        float s = conv_b[o];
#pragma unroll 8
        for (int cc = 0; cc < C; ++cc)
            s += conv_w[o * C + cc] * f0[cc][pw];
        ft[o][pw] = s;
    }
    __syncthreads();

    // ---- modulate registers and store (same coalesced pattern as load) ----
    {
        const float m = ft[c][pw];
        float* op = out + base;
#pragma unroll
        for (int r = 0; r < 8; ++r) {
            float4 a = v[2 * r + 0];
            float4 q = v[2 * r + 1];
            a.x *= m; a.y *= m; a.z *= m; a.w *= m;
            q.x *= m; q.y *= m; q.z *= m; q.w *= m;
            *(float4*)(op + (size_t)r * W)     = a;
            *(float4*)(op + (size_t)r * W + 4) = q;
        }
    }
}

extern "C" void kernel_launch(void* const* d_in, const int* in_sizes, int n_in,
                              void* d_out, int out_size, void* d_ws, size_t ws_size,
                              hipStream_t stream) {
    const float* x      = (const float*)d_in[0];
    const float* w1k    = (const float*)d_in[1];
    const float* b1k    = (const float*)d_in[2];
    const float* w2k    = (const float*)d_in[3];
    const float* b2k    = (const float*)d_in[4];
    const float* w1b    = (const float*)d_in[5];
    const float* b1b    = (const float*)d_in[6];
    const float* w2b    = (const float*)d_in[7];
    const float* b2b    = (const float*)d_in[8];
    const float* conv_w = (const float*)d_in[9];
    const float* conv_b = (const float*)d_in[10];
    float* out = (float*)d_out;

    // grid: (patch-col groups, patch rows, batch) = (16, 64, 8)
    dim3 grid(16, 64, 8);
    afpm_fused<<<grid, 256, 0, stream>>>(x, w1k, b1k, w2k, b2k,
                                         w1b, b1b, w2b, b2b,
                                         conv_w, conv_b, out);
}

// Round 3
// 240.773 us; speedup vs baseline: 1.0940x; 1.0940x over previous
//
#include <hip/hip_runtime.h>
#include <math.h>

// B=8, C=64, H=512, W=512, K=8, HID=64, nh=nw=64, L=4096
//
// Two-kernel plan:
//  A) mlp_precompute: pk[L][64], pb[L] into d_ws (1 MiB + 16 KiB). Runs once,
//     removes per-block MLP redundancy + 2 barriers from the hot kernel.
//  B) afpm_main: 512 threads = (c:64, pw:4, q:2); thread owns half a patch
//     (8 rows x 4 cols) = 8 float4 = 32 VGPR. Lane order (q,pw,c) makes each
//     vmem instruction read/write 8 fully-utilized contiguous 128B lines.
//     Dot partial pairs combine via __shfl_xor(,1). 3 barriers.
//
// R2 bug fixed here: pk/pb staging must use global patch index
// l = ph*64 + pwg*4 + pi (the ph*64 term was missing -> wrong patch kernels).

static __device__ __forceinline__ float gelu_erf(float x) {
    return 0.5f * x * (1.0f + erff(x * 0.70710678118654752f));
}

__global__ __launch_bounds__(256) void mlp_precompute(
    const float* __restrict__ w1k, const float* __restrict__ b1k,
    const float* __restrict__ w2k, const float* __restrict__ b2k,
    const float* __restrict__ w1b, const float* __restrict__ b1b,
    const float* __restrict__ w2b, const float* __restrict__ b2b,
    float* __restrict__ pk_out,   // [L][64]
    float* __restrict__ pb_out)   // [L]
{
    constexpr int HID = 64;
    const int tid = threadIdx.x;
    const int pi  = tid >> 6;          // patch within block (0..3)
    const int j   = tid & 63;          // hidden/output index
    const int l   = blockIdx.x * 4 + pi;

    const int py_i = l >> 6;
    const int px_i = l & 63;
    const float py = (float)(py_i * 8) + 4.0f - 256.0f;
    const float px = (float)(px_i * 8) + 4.0f - 256.0f;
    const float dd = sqrtf(py * py + px * px) * (1.0f / 362.03867196751236f);

    __shared__ float gk[4][HID];
    __shared__ float gb[4][HID];

    gk[pi][j] = gelu_erf(dd * w1k[j] + b1k[j]);
    gb[pi][j] = gelu_erf(dd * w1b[j] + b1b[j]);
    __syncthreads();

    float s = b2k[j];
#pragma unroll 8
    for (int h = 0; h < HID; ++h)
        s += gk[pi][h] * w2k[h * HID + j];
    pk_out[l * HID + j] = s;

    if (j == 0) {
        float t = b2b[0];
        for (int h = 0; h < HID; ++h)
            t += gb[pi][h] * w2b[h];
        pb_out[l] = t;
    }
}

__global__ __launch_bounds__(512) void afpm_main(
    const float* __restrict__ x,
    const float* __restrict__ conv_w, const float* __restrict__ conv_b,
    const float* __restrict__ pk_g,   // [L][64]
    const float* __restrict__ pb_g,   // [L]
    float* __restrict__ out)
{
    constexpr int C   = 64;
    constexpr int H   = 512;
    constexpr int W   = 512;
    constexpr int PWG = 4;

    const int tid = threadIdx.x;
    const int q   = tid & 1;            // column half (0..1): cols q*4..q*4+3
    const int pw  = (tid >> 1) & 3;     // patch within group
    const int c   = tid >> 3;           // channel
    const int pwg = blockIdx.x;         // 0..15
    const int ph  = blockIdx.y;         // 0..63
    const int b   = blockIdx.z;         // 0..7

    const int pw_glob = pwg * PWG + pw;

    __shared__ float pkL[PWG][64];      // dynamic kernels, 4 patches
    __shared__ float pbL[PWG];
    __shared__ float f0L[C][PWG];       // feats pre-conv
    __shared__ float ftL[C][PWG];       // feats post-conv

    // ---- issue pixel loads first: 8 float4, 8 full 128B lines per instr ----
    const size_t base = (((size_t)b * C + c) * H + (size_t)ph * 8) * W
                        + (size_t)pw_glob * 8 + (size_t)q * 4;
    const float* xp = x + base;
    float4 v[8];
#pragma unroll
    for (int r = 0; r < 8; ++r)
        v[r] = *(const float4*)(xp + (size_t)r * W);

    // ---- stage pk/pb into LDS; global patch l = ph*64 + pwg*4 + pi ----
    const int lbase = ph * 64 + pwg * 4;
    if (tid < 256)
        pkL[tid >> 6][tid & 63] = pk_g[((size_t)lbase + (tid >> 6)) * 64 + (tid & 63)];
    else if (tid < 256 + PWG)
        pbL[tid - 256] = pb_g[lbase + (tid - 256)];
    __syncthreads();

    // ---- partial dot over this thread's half-patch ----
    float s = 0.0f;
#pragma unroll
    for (int r = 0; r < 8; ++r) {
        const float4 a = v[r];
        const int k0 = r * 8 + q * 4;
        s += a.x * pkL[pw][k0 + 0] + a.y * pkL[pw][k0 + 1]
           + a.z * pkL[pw][k0 + 2] + a.w * pkL[pw][k0 + 3];
    }
    s += __shfl_xor(s, 1);              // combine the two column halves
    if (q == 0)
        f0L[c][pw] = s + pbL[pw];
    __syncthreads();

    // ---- 1x1 conv across channels (first 256 threads) ----
    if (tid < 256) {
        const int o   = tid >> 2;
        const int pw2 = tid & 3;
        float t = conv_b[o];
#pragma unroll 8
        for (int cc = 0; cc < C; ++cc)
            t += conv_w[o * C + cc] * f0L[cc][pw2];
        ftL[o][pw2] = t;
    }
    __syncthreads();

    // ---- modulate + store (same fully-coalesced pattern) ----
    const float m = ftL[c][pw];
    float* op = out + base;
#pragma unroll
    for (int r = 0; r < 8; ++r) {
        float4 a = v[r];
        a.x *= m; a.y *= m; a.z *= m; a.w *= m;
        *(float4*)(op + (size_t)r * W) = a;
    }
}

extern "C" void kernel_launch(void* const* d_in, const int* in_sizes, int n_in,
                              void* d_out, int out_size, void* d_ws, size_t ws_size,
                              hipStream_t stream) {
    const float* x      = (const float*)d_in[0];
    const float* w1k    = (const float*)d_in[1];
    const float* b1k    = (const float*)d_in[2];
    const float* w2k    = (const float*)d_in[3];
    const float* b2k    = (const float*)d_in[4];
    const float* w1b    = (const float*)d_in[5];
    const float* b1b    = (const float*)d_in[6];
    const float* w2b    = (const float*)d_in[7];
    const float* b2b    = (const float*)d_in[8];
    const float* conv_w = (const float*)d_in[9];
    const float* conv_b = (const float*)d_in[10];
    float* out = (float*)d_out;

    constexpr int L = 64 * 64;
    float* pk = (float*)d_ws;            // L*64 floats = 1 MiB
    float* pb = pk + (size_t)L * 64;     // L floats

    mlp_precompute<<<L / 4, 256, 0, stream>>>(w1k, b1k, w2k, b2k,
                                              w1b, b1b, w2b, b2b, pk, pb);

    dim3 grid(16, 64, 8);
    afpm_main<<<grid, 512, 0, stream>>>(x, conv_w, conv_b, pk, pb, out);
}